// Round 7
// baseline (407.644 us; speedup 1.0000x reference)
//
#include <hip/hip_runtime.h>
#include <hip/hip_bf16.h>

// CausalMLA: B=2, L=2048, D=2048, H=16, HD=128, LD=32. Inputs fp32 or bf16
// (runtime-detected); pipeline bf16/MFMA; output dtype follows input.
// R5: algebraic folds — V compress folded into weights, decompress into Wo.
// R6: fold_bias parallelized. R7: lean split QK / V-fold GEMMs.
// R8: flash32 1 q-tile/block, 4-wave KV split + flash-decode merge.
// R9: prep fused; flash 64-key chunks. R10: v_fold merged into qk dispatch
//     (disjoint block branch, VGPR stays 72); flash load prefetch + exp2.
// R11: fold stage dissolved: fold_vw/fold_ow computed fp32-direct from
//     original Wv/Wvc/Wo/Wd inside prep_all (kills WvB conv + WtO transpose
//     = ~72MB intermediate traffic); bvF in prep_all; boF finalize as 8
//     extra blocks of gemm_qkv. Dispatches 6 -> 5.

#define Bsz 2
#define Lseq 2048
#define Dmod 2048
#define Hn 16
#define HDim 128
#define LDim 32

typedef __bf16 bf16x8 __attribute__((ext_vector_type(8)));
typedef float f32x4 __attribute__((ext_vector_type(4)));
typedef __hip_bfloat16 bf16;

#define GLDS16(g, l)                                                    \
  __builtin_amdgcn_global_load_lds(                                     \
      (const __attribute__((address_space(1))) unsigned int*)(g),       \
      (__attribute__((address_space(3))) unsigned int*)(l), 16, 0, 0)

// ---- small-constants area layout (bf16 element offsets inside `small`) ----
#define SM_COS 0
#define SM_SIN 131072
#define SM_WC 262144     // Wqc|Wkc|Wvc 3*4096
#define SM_BC 274432     // bqc|bkc|bvc 3*32
#define SM_WD 274528     // 4096
#define SM_BD 278624     // 128
#define SM_BO 278752     // 2048
#define SM_BQKV 280800   // bq|bk|bv 3*2048
#define SM_TOT 286944

// ---------------- dtype detector ----------------
__global__ void detect_dtype(const ushort* __restrict__ x, int* __restrict__ flag) {
  int t = threadIdx.x;  // 64 threads
  int bad = 0;
  for (int k = 0; k < 4; ++k) {
    ushort u = x[t * 4 + k];
    int ex = (u >> 7) & 0xFF;
    if (ex >= 0xC0) bad = 1;
  }
  unsigned long long b = __ballot(bad);
  if (t == 0) *flag = (b != 0ULL) ? 1 : 0;  // 1 = inputs are fp32
}

__device__ inline void conv8(const void* src, size_t so, bf16* dst, size_t dof, int f32) {
  if (f32) {
    const float* s = (const float*)src + so;
    bf16 tmp[8] __attribute__((aligned(16)));
    for (int j = 0; j < 8; ++j) tmp[j] = __float2bfloat16(s[j]);
    *(uint4*)&dst[dof] = *(uint4*)tmp;
  } else {
    *(uint4*)&dst[dof] = *(const uint4*)((const ushort*)src + so);
  }
}

__device__ inline float cv1(const void* s, size_t i, int f32) {
  return f32 ? ((const float*)s)[i] : __bfloat162float(((const bf16*)s)[i]);
}

// ---------------- prep_all: transpose2 | conv x | small-prep | fbp | fold_vw | fold_ow | bvF ----------------
// block ranges (cumulative): T2 [0,2048) CX [2048,6144) PREP [6144,6304)
// FBP [6304,6560) FVW [6560,7072) FOW [7072,7328) BVF [7328,7330)
#define PB_T2 0
#define PB_CX 2048
#define PB_PREP 6144
#define PB_FBP 6304
#define PB_FVW 6560
#define PB_FOW 7072
#define PB_BVF 7328
#define NB_PREP_ALL 7330

__global__ __launch_bounds__(256) void prep_all(
    const void* xS, const void* cosS, const void* sinS, const void* WqS,
    const void* WkS, const void* WvS, const void* WoS, const void* WqcS,
    const void* WkcS, const void* WvcS, const void* bqcS, const void* bkcS,
    const void* bvcS, const void* WdS, const void* bdS, const void* boS,
    const void* bqS, const void* bkS, const void* bvS,
    bf16* __restrict__ xb, bf16* __restrict__ WtQK, bf16* __restrict__ small,
    bf16* __restrict__ wctG, float* __restrict__ bo_part,
    bf16* __restrict__ Wvt, bf16* __restrict__ Wot, float* __restrict__ bvF,
    const int* __restrict__ flagp) {
  __shared__ __align__(16) char shm[16896];
  int f32 = *flagp;
  int blk = blockIdx.x;
  int t = threadIdx.x;

  if (blk < PB_CX) {
    // --- weight transpose (Wq, Wk) ---
    float (*tile)[65] = (float(*)[65])shm;
    int z = blk >> 10, rem = blk & 1023;
    const void* W = (z == 0) ? WqS : WkS;
    bf16* Wt = WtQK + (size_t)z * 2048 * 2048;
    int n0 = (rem & 31) * 64, k0 = (rem >> 5) * 64;
    int x = (t & 7) * 8, y = t >> 3;
    for (int p = 0; p < 2; ++p) {
      int r = y + p * 32;
      if (f32) {
        const float* src = (const float*)W + (size_t)(k0 + r) * 2048 + n0 + x;
        float4 a = *(const float4*)src;
        float4 b2 = *(const float4*)(src + 4);
        tile[r][x + 0] = a.x; tile[r][x + 1] = a.y; tile[r][x + 2] = a.z; tile[r][x + 3] = a.w;
        tile[r][x + 4] = b2.x; tile[r][x + 5] = b2.y; tile[r][x + 6] = b2.z; tile[r][x + 7] = b2.w;
      } else {
        const ushort* src = (const ushort*)W + (size_t)(k0 + r) * 2048 + n0 + x;
        uint4 u = *(const uint4*)src;
        bf16* e = (bf16*)&u;
        for (int jj = 0; jj < 8; ++jj) tile[r][x + jj] = __bfloat162float(e[jj]);
      }
    }
    __syncthreads();
    for (int p = 0; p < 2; ++p) {
      int n = y + p * 32;
      bf16 tmp[8] __attribute__((aligned(16)));
      for (int jj = 0; jj < 8; ++jj) tmp[jj] = __float2bfloat16(tile[x + jj][n]);
      *(uint4*)&Wt[(size_t)(n0 + n) * 2048 + k0 + x] = *(uint4*)tmp;
    }
  } else if (blk < PB_PREP) {
    // --- x -> bf16 copy ---
    size_t e = ((size_t)(blk - PB_CX) * 256 + t) * 8;
    conv8(xS, e, xb, e, f32);
  } else if (blk < PB_FBP) {
    // --- small-area + wctG prep ---
    int tid = (blk - PB_PREP) * 256 + t;  // 0..40959
    if (tid < SM_TOT / 8) {
      size_t e = (size_t)tid * 8;
      const void* src;
      size_t so;
      if (e < SM_SIN) { src = cosS; so = e - SM_COS; }
      else if (e < SM_WC) { src = sinS; so = e - SM_SIN; }
      else if (e < SM_BC) { size_t r = e - SM_WC; src = (r < 4096) ? WqcS : (r < 8192) ? WkcS : WvcS; so = r & 4095; }
      else if (e < SM_WD) { size_t r = e - SM_BC; src = (r < 32) ? bqcS : (r < 64) ? bkcS : bvcS; so = r & 31; }
      else if (e < SM_BD) { src = WdS; so = e - SM_WD; }
      else if (e < SM_BO) { src = bdS; so = e - SM_BD; }
      else if (e < SM_BQKV) { src = boS; so = e - SM_BO; }
      else { size_t r = e - SM_BQKV; src = (r < 2048) ? bqS : (r < 4096) ? bkS : bvS; so = r & 2047; }
      conv8(src, so, small, e, f32);
    } else {
      int idx = tid - SM_TOT / 8;
      for (int i = idx; i < 12288; i += 40960 - SM_TOT / 8) {
        int reg = i >> 12, rem2 = i & 4095, n = rem2 >> 7, k = rem2 & 127;
        const void* src = (reg == 0) ? WqcS : (reg == 1) ? WkcS : WvcS;
        wctG[i] = __float2bfloat16(cv1(src, (size_t)k * 32 + n, f32));
      }
    }
  } else if (blk < PB_FVW) {
    // --- fold_bias partial: bo_part[kb][col] ---
    float* red = (float*)shm;
    int rem = blk - PB_FBP;
    int nb = rem & 15, kb = rem >> 4;
    int col = nb * 128 + (t & 127);
    int half = t >> 7;
    float s = 0.f;
    int kbase = kb * 128 + half * 64;
    for (int i = 0; i < 64; ++i) {
      int k = kbase + i;
      s += cv1(bdS, k & 127, f32) * cv1(WoS, (size_t)k * 2048 + col, f32);
    }
    red[t] = s;
    __syncthreads();
    if (half == 0) bo_part[kb * 2048 + col] = red[t] + red[t + 128];
  } else if (blk < PB_FOW) {
    // --- fold_vw fp32-direct: W~vt[(h*32+e)][k] = sum_hd Wv[k][h*128+hd]*Wvc[hd][e] ---
    float* wvc = (float*)shm;  // 4096 f32
    for (int i = t; i < 4096; i += 256) wvc[i] = cv1(WvcS, i, f32);
    __syncthreads();
    int rem = blk - PB_FVW;
    int h = rem >> 5, kb = rem & 31;
    int k = kb * 64 + (t >> 2);
    int e0 = (t & 3) * 8;
    float acc[8] = {};
    for (int hd0 = 0; hd0 < 128; hd0 += 8) {
      float wv[8];
      for (int j = 0; j < 8; ++j)
        wv[j] = cv1(WvS, (size_t)k * 2048 + h * 128 + hd0 + j, f32);
      for (int j = 0; j < 8; ++j)
        for (int e = 0; e < 8; ++e)
          acc[e] += wv[j] * wvc[(hd0 + j) * 32 + e0 + e];
    }
    for (int e = 0; e < 8; ++e)
      Wvt[(size_t)(h * 32 + e0 + e) * 2048 + k] = __float2bfloat16(acc[e]);
  } else if (blk < PB_BVF) {
    // --- fold_ow fp32-direct: W~ot[d][h*32+e] = sum_hd Wd[e][hd]*Wo[h*128+hd][d] ---
    float* wd = (float*)shm;  // 4096 f32
    for (int i = t; i < 4096; i += 256) wd[i] = cv1(WdS, i, f32);
    __syncthreads();
    int rem = blk - PB_FOW;
    int h = rem >> 4, db = rem & 15;
    int d = db * 128 + (t & 127);
    int half = t >> 7;
    float acc[32] = {};
    for (int hd = half * 64; hd < half * 64 + 64; ++hd) {
      float wo = cv1(WoS, (size_t)(h * 128 + hd) * 2048 + d, f32);
      for (int e = 0; e < 32; ++e) acc[e] += wd[e * 128 + hd] * wo;
    }
    __syncthreads();
    float* xch = (float*)shm;  // 128 x 33 f32 (padded)
    if (half) {
      for (int e = 0; e < 32; ++e) xch[(t & 127) * 33 + e] = acc[e];
    }
    __syncthreads();
    if (!half) {
      bf16 out[32] __attribute__((aligned(16)));
      for (int e = 0; e < 32; ++e)
        out[e] = __float2bfloat16(acc[e] + xch[(t & 127) * 33 + e]);
      for (int q = 0; q < 4; ++q)
        *(uint4*)&Wot[(size_t)d * 512 + h * 32 + q * 8] = *(uint4*)&out[q * 8];
    }
  } else {
    // --- bvF = bv@Wvc(per-head) + bvc ---
    int tid = (blk - PB_BVF) * 256 + t;  // 0..511
    if (tid < 512) {
      int h = tid >> 5, e = tid & 31;
      float s = cv1(bvcS, e, f32);
      for (int hd = 0; hd < 128; ++hd)
        s += cv1(bvS, h * 128 + hd, f32) * cv1(WvcS, (size_t)hd * 32 + e, f32);
      bvF[tid] = s;
    }
  }
}

// ---------------- merged QKV: 0..1023 QK+RoPE+compress | 1024..1535 V-fold | 1536..1543 boF ----------------
#define ESTR 136
__global__ __launch_bounds__(256) void gemm_qkv(
    const bf16* __restrict__ A, const bf16* __restrict__ Bt,
    const bf16* __restrict__ Wvt, const bf16* __restrict__ small,
    const bf16* __restrict__ wctG, const float* __restrict__ bvF,
    const void* boS, const float* __restrict__ bo_part,
    bf16* __restrict__ qc, bf16* __restrict__ kc, bf16* __restrict__ vcT,
    float* __restrict__ boF, const int* __restrict__ flagp) {
  __shared__ bf16 sh[128 * ESTR];  // 34816 B; first 16KB doubles as lA|lB
  const int K = 2048;
  int id = blockIdx.x;
  int t = threadIdx.x;
  int lane = t & 63, w = t >> 6;
  int qd = lane >> 4, ln = lane & 15;

  if (id < 1024) {
    // ---- QK path: bn fastest ----
    bf16* lA = sh;
    bf16* lB = sh + 4096;
    int bn = id & 31, bm = id >> 5;
    int reg = bn >> 4, h = bn & 15;
    int wm = (w >> 1) * 64, wn = (w & 1) * 64;

    f32x4 acc[4][4] = {};
    const bf16* Ab = A + (size_t)(bm * 128) * K;
    const bf16* Bb = Bt + (size_t)(bn * 128) * K;

    for (int kt = 0; kt < K; kt += 32) {
      for (int p = 0; p < 2; ++p) {
        int slot = t + p * 256;
        int r = slot >> 2, c = (slot & 3) * 8;
        GLDS16(&Ab[(size_t)r * K + kt + c], &lA[slot * 8]);
        GLDS16(&Bb[(size_t)r * K + kt + c], &lB[slot * 8]);
      }
      __syncthreads();
      bf16x8 af[4], bfr[4];
      for (int i = 0; i < 4; ++i) af[i] = *(bf16x8*)&lA[(wm + i * 16 + ln) * 32 + qd * 8];
      for (int j = 0; j < 4; ++j) bfr[j] = *(bf16x8*)&lB[(wn + j * 16 + ln) * 32 + qd * 8];
      for (int i = 0; i < 4; ++i)
        for (int j = 0; j < 4; ++j)
          acc[i][j] = __builtin_amdgcn_mfma_f32_16x16x32_bf16(af[i], bfr[j], acc[i][j], 0, 0, 0);
      __syncthreads();
    }

    // epilogue 1: acc + bias -> LDS tile
    for (int j = 0; j < 4; ++j) {
      int col = wn + j * 16 + ln;
      float bv = __bfloat162float(small[SM_BQKV + bn * 128 + col]);
      for (int i = 0; i < 4; ++i)
        for (int r = 0; r < 4; ++r)
          sh[(wm + i * 16 + qd * 4 + r) * ESTR + col] = __float2bfloat16(acc[i][j][r] + bv);
    }
    __syncthreads();

    // epilogue 2: RoPE + compress 32 l-rows per wave
    int r0 = w * 32;
    int b = bm >> 4;
    int bh = b * Hn + h;
    bf16x8 bfr2[2][4];
    for (int nt = 0; nt < 2; ++nt)
      for (int kt = 0; kt < 4; ++kt)
        bfr2[nt][kt] = *(const bf16x8*)&wctG[reg * 4096 + (nt * 16 + ln) * 128 + kt * 32 + qd * 8];
    float bc[2];
    bc[0] = __bfloat162float(small[SM_BC + reg * 32 + ln]);
    bc[1] = __bfloat162float(small[SM_BC + reg * 32 + 16 + ln]);

    for (int mt = 0; mt < 2; ++mt) {
      int lb = r0 + mt * 16 + ln;
      int lg2 = (bm & 15) * 128 + lb;
      f32x4 c2[2] = {};
      for (int kt = 0; kt < 4; ++kt) {
        uint4 u = *(uint4*)&sh[lb * ESTR + kt * 32 + qd * 8];
        bf16* e8 = (bf16*)&u;
        int pbase = kt * 16 + qd * 4;
        uint2 cu = *(const uint2*)&small[SM_COS + (size_t)lg2 * 64 + pbase];
        uint2 su = *(const uint2*)&small[SM_SIN + (size_t)lg2 * 64 + pbase];
        const bf16* cp = (const bf16*)&cu;
        const bf16* sp = (const bf16*)&su;
        for (int j = 0; j < 4; ++j) {
          float cvv = __bfloat162float(cp[j]);
          float svv = __bfloat162float(sp[j]);
          float ev = __bfloat162float(e8[2 * j]);
          float ov = __bfloat162float(e8[2 * j + 1]);
          e8[2 * j] = __float2bfloat16(ev * cvv - ov * svv);
          e8[2 * j + 1] = __float2bfloat16(ev * svv + ov * cvv);
        }
        bf16x8 a = *(bf16x8*)&u;
        c2[0] = __builtin_amdgcn_mfma_f32_16x16x32_bf16(a, bfr2[0][kt], c2[0], 0, 0, 0);
        c2[1] = __builtin_amdgcn_mfma_f32_16x16x32_bf16(a, bfr2[1][kt], c2[1], 0, 0, 0);
      }
      int lgbase = (bm & 15) * 128 + r0 + mt * 16 + qd * 4;
      bf16* dst = (reg == 0) ? qc : kc;
      for (int nt = 0; nt < 2; ++nt)
        for (int r = 0; r < 4; ++r)
          dst[((size_t)bh * Lseq + lgbase + r) * 32 + nt * 16 + ln] =
              __float2bfloat16(c2[nt][r] + bc[nt]);
    }
  } else if (id < 1536) {
    // ---- V-fold path: vcT[(b*512+n)][l] = x @ W~vt^T + bvF ----
    bf16* lA = sh;
    bf16* lB = sh + 2048;  // 64*32 elements each
    int rem = id - 1024;
    int nb = rem & 7, bm = rem >> 3;
    int wm = (w >> 1) * 32, wn = (w & 1) * 32;

    f32x4 acc[2][2] = {};
    const bf16* Ab = A + (size_t)(bm * 64) * K;
    const bf16* Bb = Wvt + (size_t)(nb * 64) * K;

    int r = t >> 2, c = (t & 3) * 8;
    for (int kt = 0; kt < K; kt += 32) {
      GLDS16(&Ab[(size_t)r * K + kt + c], &lA[t * 8]);
      GLDS16(&Bb[(size_t)r * K + kt + c], &lB[t * 8]);
      __syncthreads();
      bf16x8 af[2], bfr[2];
      for (int i = 0; i < 2; ++i) af[i] = *(bf16x8*)&lA[(wm + i * 16 + ln) * 32 + qd * 8];
      for (int j = 0; j < 2; ++j) bfr[j] = *(bf16x8*)&lB[(wn + j * 16 + ln) * 32 + qd * 8];
      for (int i = 0; i < 2; ++i)
        for (int j = 0; j < 2; ++j)
          acc[i][j] = __builtin_amdgcn_mfma_f32_16x16x32_bf16(af[i], bfr[j], acc[i][j], 0, 0, 0);
      __syncthreads();
    }

    int b = bm >> 5;
    for (int j = 0; j < 2; ++j) {
      int n = nb * 64 + wn + j * 16 + ln;
      float bb = bvF[n];
      for (int i = 0; i < 2; ++i) {
        int lloc = (bm & 31) * 64 + wm + i * 16 + qd * 4;
        bf16 p4[4] __attribute__((aligned(8)));
        for (int rr = 0; rr < 4; ++rr) p4[rr] = __float2bfloat16(acc[i][j][rr] + bb);
        *(uint2*)&vcT[((size_t)(b * 512 + n)) * 2048 + lloc] = *(uint2*)p4;
      }
    }
  } else {
    // ---- boF finalize: boF = bo + sum_kb bo_part ----
    int f32 = *flagp;
    int tid = (id - 1536) * 256 + t;  // 0..2047
    float s = cv1(boS, tid, f32);
    for (int kb = 0; kb < 16; ++kb) s += bo_part[kb * 2048 + tid];
    boF[tid] = s;
  }
}

// ---------------- output GEMM: d_out = attn @ Wot^T + boF (fp32 bias), K=512 ----------------
__global__ __launch_bounds__(256) void gemm_bias_out(const bf16* __restrict__ A,
                                                     const bf16* __restrict__ Bt,
                                                     const float* __restrict__ bias,
                                                     void* __restrict__ C,
                                                     int M, int N, int K,
                                                     const int* __restrict__ flagp) {
  __shared__ bf16 lA[128 * 32];
  __shared__ bf16 lB[128 * 32];
  int f32out = *flagp;
  int bm = blockIdx.y, bn = blockIdx.x;
  int t = threadIdx.x;
  int lane = t & 63, w = t >> 6;
  int wm = (w >> 1) * 64, wn = (w & 1) * 64;
  int qd = lane >> 4, ln = lane & 15;

  f32x4 acc[4][4] = {};
  const bf16* Ab = A + (size_t)(bm * 128) * K;
  const bf16* Bb = Bt + (size_t)(bn * 128) * K;

  for (int kt = 0; kt < K; kt += 32) {
    for (int p = 0; p < 2; ++p) {
      int slot = t + p * 256;
      int r = slot >> 2, c = (slot & 3) * 8;
      GLDS16(&Ab[(size_t)r * K + kt + c], &lA[slot * 8]);
      GLDS16(&Bb[(size_t)r * K + kt + c], &lB[slot * 8]);
    }
    __syncthreads();
    bf16x8 af[4], bfr[4];
    for (int i = 0; i < 4; ++i) af[i] = *(bf16x8*)&lA[(wm + i * 16 + ln) * 32 + qd * 8];
    for (int j = 0; j < 4; ++j) bfr[j] = *(bf16x8*)&lB[(wn + j * 16 + ln) * 32 + qd * 8];
    for (int i = 0; i < 4; ++i)
      for (int j = 0; j < 4; ++j)
        acc[i][j] = __builtin_amdgcn_mfma_f32_16x16x32_bf16(af[i], bfr[j], acc[i][j], 0, 0, 0);
    __syncthreads();
  }
  for (int i = 0; i < 4; ++i)
    for (int j = 0; j < 4; ++j) {
      int col = bn * 128 + wn + j * 16 + ln;
      float bv = bias[col];
      for (int r = 0; r < 4; ++r) {
        int row = bm * 128 + wm + i * 16 + qd * 4 + r;
        float v = acc[i][j][r] + bv;
        if (f32out) ((float*)C)[(size_t)row * N + col] = v;
        else ((bf16*)C)[(size_t)row * N + col] = __float2bfloat16(v);
      }
    }
}

// ---------------- flash attention: 64-key chunks, prefetched loads, exp2 softmax ----------------
__global__ __launch_bounds__(256) void flash32(const bf16* __restrict__ qc,
                                               const bf16* __restrict__ kc,
                                               const bf16* __restrict__ vcT,
                                               bf16* __restrict__ attn) {
  __shared__ bf16 pbuf[4][16 * 72];     // 9216 B
  __shared__ float oL[4][16][33];       // 8448 B
  __shared__ float mL[4][16];
  __shared__ float lsL[4][16];
  int t = threadIdx.x;
  int lane = t & 63, w = t >> 6;
  int qd = lane >> 4, ln = lane & 15;
  int blk = blockIdx.x;                 // grid 4096 = 32 bh x 128 q-tiles
  int j = blk & 127;
  int bh = blk >> 7, h = bh & 15, b = bh >> 4;
  int q0 = j * 16;

  bf16x8 qf = *(const bf16x8*)&qc[((size_t)bh * Lseq + q0 + ln) * 32 + qd * 8];

  f32x4 o0 = {}, o1 = {};
  float m[4], ls[4];
  for (int r = 0; r < 4; ++r) { m[r] = -1e30f; ls[r] = 0.f; }
  const float scale2 = 0.17677669529663687f * 1.4426950408889634f;

  int n64 = (q0 + 16 + 63) >> 6;        // causal KV chunks of 64
  int nw = (n64 + 3) >> 2;
  int c0 = w * nw;
  int c1 = min(c0 + nw, n64);

  bf16* pb = pbuf[w];
  bf16x8 kf[4];
  if (c0 < c1) {
    int k0 = c0 * 64;
    for (int c = 0; c < 4; ++c)
      kf[c] = *(const bf16x8*)&kc[((size_t)bh * Lseq + k0 + c * 16 + ln) * 32 + qd * 8];
  }
  for (int ci = c0; ci < c1; ++ci) {
    int k0 = ci * 64;
    f32x4 s[4];
    for (int c = 0; c < 4; ++c) {
      f32x4 z = {};
      s[c] = __builtin_amdgcn_mfma_f32_16x16x32_bf16(qf, kf[c], z, 0, 0, 0);
    }
    size_t vbase = ((size_t)bh * 32 + ln) * Lseq + k0 + qd * 8;
    bf16x8 vf00 = *(const bf16x8*)&vcT[vbase];
    bf16x8 vf01 = *(const bf16x8*)&vcT[vbase + 32];
    bf16x8 vf10 = *(const bf16x8*)&vcT[vbase + (size_t)16 * Lseq];
    bf16x8 vf11 = *(const bf16x8*)&vcT[vbase + (size_t)16 * Lseq + 32];
    if (ci + 1 < c1) {
      int k0n = k0 + 64;
      for (int c = 0; c < 4; ++c)
        kf[c] = *(const bf16x8*)&kc[((size_t)bh * Lseq + k0n + c * 16 + ln) * 32 + qd * 8];
    }
    float sv[4][4], alpha[4];
    for (int r = 0; r < 4; ++r) {
      int qrow = q0 + qd * 4 + r;
      for (int c = 0; c < 4; ++c)
        sv[c][r] = (k0 + c * 16 + ln <= qrow) ? s[c][r] * scale2 : -1e30f;
    }
    for (int r = 0; r < 4; ++r) {
      float mx = fmaxf(fmaxf(sv[0][r], sv[1][r]), fmaxf(sv[2][r], sv[3][r]));
      for (int off = 1; off < 16; off <<= 1) mx = fmaxf(mx, __shfl_xor(mx, off, 64));
      float mn = fmaxf(m[r], mx);
      alpha[r] = exp2f(m[r] - mn);
      m[r] = mn;
      float rs = 0.f;
      for (int c = 0; c < 4; ++c) { sv[c][r] = exp2f(sv[c][r] - mn); rs += sv[c][r]; }
      ls[r] = ls[r] * alpha[r] + rs;
      o0[r] *= alpha[r];
      o1[r] *= alpha[r];
    }
    for (int r = 0; r < 4; ++r)
      for (int c = 0; c < 4; ++c)
        pb[(qd * 4 + r) * 72 + c * 16 + ln] = __float2bfloat16(sv[c][r]);
    asm volatile("s_waitcnt lgkmcnt(0)" ::: "memory");
    bf16x8 pf0 = *(bf16x8*)&pb[ln * 72 + qd * 8];
    bf16x8 pf1 = *(bf16x8*)&pb[ln * 72 + 32 + qd * 8];
    o0 = __builtin_amdgcn_mfma_f32_16x16x32_bf16(pf0, vf00, o0, 0, 0, 0);
    o0 = __builtin_amdgcn_mfma_f32_16x16x32_bf16(pf1, vf01, o0, 0, 0, 0);
    o1 = __builtin_amdgcn_mfma_f32_16x16x32_bf16(pf0, vf10, o1, 0, 0, 0);
    o1 = __builtin_amdgcn_mfma_f32_16x16x32_bf16(pf1, vf11, o1, 0, 0, 0);
  }

  for (int r = 0; r < 4; ++r)
    for (int off = 1; off < 16; off <<= 1) ls[r] += __shfl_xor(ls[r], off, 64);

  for (int r = 0; r < 4; ++r) {
    int row = qd * 4 + r;
    oL[w][row][ln] = o0[r];
    oL[w][row][16 + ln] = o1[r];
    if (ln == 0) { mL[w][row] = m[r]; lsL[w][row] = ls[r]; }
  }
  __syncthreads();

  for (int idx = t; idx < 512; idx += 256) {
    int row = idx >> 5, col = idx & 31;
    float m0 = mL[0][row], m1 = mL[1][row], m2 = mL[2][row], m3 = mL[3][row];
    float ms = fmaxf(fmaxf(m0, m1), fmaxf(m2, m3));
    float e0 = exp2f(m0 - ms), e1 = exp2f(m1 - ms);
    float e2 = exp2f(m2 - ms), e3 = exp2f(m3 - ms);
    float lsum = lsL[0][row] * e0 + lsL[1][row] * e1 + lsL[2][row] * e2 + lsL[3][row] * e3;
    float val = oL[0][row][col] * e0 + oL[1][row][col] * e1 +
                oL[2][row][col] * e2 + oL[3][row][col] * e3;
    int l = q0 + row;
    attn[((size_t)(b * Lseq + l)) * 512 + h * 32 + col] = __float2bfloat16(val / lsum);
  }
}

extern "C" void kernel_launch(void* const* d_in, const int* in_sizes, int n_in,
                              void* d_out, int out_size, void* d_ws, size_t ws_size,
                              hipStream_t stream) {
  const void* x = d_in[0];
  const void* cosS = d_in[1];
  const void* sinS = d_in[2];
  const void* Wq = d_in[3];
  const void* bq = d_in[4];
  const void* Wk = d_in[5];
  const void* bk = d_in[6];
  const void* Wv = d_in[7];
  const void* bv = d_in[8];
  const void* Wqc = d_in[9];
  const void* bqc = d_in[10];
  const void* Wkc = d_in[11];
  const void* bkc = d_in[12];
  const void* Wvc = d_in[13];
  const void* bvc = d_in[14];
  const void* Wd = d_in[15];
  const void* bd = d_in[16];
  const void* Wo = d_in[17];
  const void* bo = d_in[18];

  char* ws = (char*)d_ws;
  size_t off = 0;
  auto alloc = [&](size_t bytes) {
    char* p = ws + off;
    off += (bytes + 255) & ~(size_t)255;
    return p;
  };
  int* flag = (int*)alloc(256);
  bf16* small = (bf16*)alloc((size_t)SM_TOT * 2);
  bf16* wctG = (bf16*)alloc((size_t)12288 * 2);
  bf16* xb = (bf16*)alloc((size_t)4096 * 2048 * 2);
  bf16* WtQK = (bf16*)alloc((size_t)4096 * 2048 * 2);
  bf16* Wvt = (bf16*)alloc((size_t)512 * 2048 * 2);
  bf16* Wot = (bf16*)alloc((size_t)2048 * 512 * 2);
  float* bo_part = (float*)alloc((size_t)16 * 2048 * 4);
  float* boF = (float*)alloc((size_t)2048 * 4);
  float* bvF = (float*)alloc((size_t)512 * 4);
  bf16* qcW = (bf16*)alloc((size_t)65536 * 32 * 2);
  bf16* kcW = (bf16*)alloc((size_t)65536 * 32 * 2);
  bf16* vcTW = (bf16*)alloc((size_t)65536 * 32 * 2);
  bf16* attnW = (bf16*)alloc((size_t)4096 * 512 * 2);

  dim3 tb(256);
  detect_dtype<<<1, 64, 0, stream>>>((const ushort*)x, flag);
  prep_all<<<NB_PREP_ALL, tb, 0, stream>>>(
      x, cosS, sinS, Wq, Wk, Wv, Wo, Wqc, Wkc, Wvc, bqc, bkc, bvc, Wd, bd, bo,
      bq, bk, bv, xb, WtQK, small, wctG, bo_part, Wvt, Wot, bvF, flag);
  gemm_qkv<<<1544, tb, 0, stream>>>(xb, WtQK, Wvt, small, wctG, bvF, bo, bo_part,
                                    qcW, kcW, vcTW, boF, flag);
  flash32<<<4096, tb, 0, stream>>>(qcW, kcW, vcTW, attnW);
  gemm_bias_out<<<dim3(16, 32), tb, 0, stream>>>(attnW, Wot, boF, d_out, 4096, 2048,
                                                 512, flag);
}

// Round 8
// 380.951 us; speedup vs baseline: 1.0701x; 1.0701x over previous
//
#include <hip/hip_runtime.h>
#include <hip/hip_bf16.h>

// CausalMLA: B=2, L=2048, D=2048, H=16, HD=128, LD=32. Inputs fp32 or bf16
// (runtime-detected); pipeline bf16/MFMA; output dtype follows input.
// R5: algebraic folds — V compress folded into weights, decompress into Wo.
// R6: fold_bias parallelized. R7: lean split QK / V-fold GEMMs.
// R8: flash32 1 q-tile/block, 4-wave KV split + flash-decode merge.
// R9: prep fused; flash 64-key chunks. R10: v_fold merged into qk dispatch
//     (disjoint block branch, VGPR stays 72); flash load prefetch + exp2.
// R11 (REVERTED): fp32-direct folds inside prep_all raised prep_all's
//     max-branch VGPR -> occupancy collapse for all copy blocks (+13us).
// R12: back to R10 structure (light prep_all + separate fold_all); dead wdtG
//     dropped; detect_dtype dispatch removed (prep blocks self-detect via
//     wave-0 ballot, block 0 publishes flag); prep blocks reordered heavy-
//     first; flash32 gains T13 defer-max (skip rescale when __all(mx<=m+8)).

#define Bsz 2
#define Lseq 2048
#define Dmod 2048
#define Hn 16
#define HDim 128
#define LDim 32

typedef __bf16 bf16x8 __attribute__((ext_vector_type(8)));
typedef float f32x4 __attribute__((ext_vector_type(4)));
typedef __hip_bfloat16 bf16;

#define GLDS16(g, l)                                                    \
  __builtin_amdgcn_global_load_lds(                                     \
      (const __attribute__((address_space(1))) unsigned int*)(g),       \
      (__attribute__((address_space(3))) unsigned int*)(l), 16, 0, 0)

// ---- small-constants area layout (bf16 element offsets inside `small`) ----
#define SM_COS 0
#define SM_SIN 131072
#define SM_WC 262144     // Wqc|Wkc|Wvc 3*4096
#define SM_BC 274432     // bqc|bkc|bvc 3*32
#define SM_WD 274528     // 4096 (row-major Wd[e][hd] — used by fold_ow)
#define SM_BD 278624     // 128
#define SM_BO 278752     // 2048
#define SM_BQKV 280800   // bq|bk|bv 3*2048
#define SM_TOT 286944

__device__ inline void conv8(const void* src, size_t so, bf16* dst, size_t dof, int f32) {
  if (f32) {
    const float* s = (const float*)src + so;
    bf16 tmp[8] __attribute__((aligned(16)));
    for (int j = 0; j < 8; ++j) tmp[j] = __float2bfloat16(s[j]);
    *(uint4*)&dst[dof] = *(uint4*)tmp;
  } else {
    *(uint4*)&dst[dof] = *(const uint4*)((const ushort*)src + so);
  }
}

__device__ inline float cv1(const void* s, size_t i, int f32) {
  return f32 ? ((const float*)s)[i] : __bfloat162float(((const bf16*)s)[i]);
}

// ---------------- prep_all: fbp | transpose3 | conv Wv | conv x | small-prep ----------------
// heavy-first ordering so long blocks don't define the dispatch tail.
#define PB_FBP 0       // [0,256)    fold_bias partial
#define PB_T3 256      // [256,3328) Wq/Wk/Wo transpose
#define PB_WV 3328     // [3328,5376) Wv -> bf16
#define PB_CX 5376     // [5376,9472) x -> bf16
#define PB_SM 9472     // [9472,9632) small-area + wctG
#define NB_PREP_ALL 9632

__global__ __launch_bounds__(256) void prep_all(
    const void* xS, const void* cosS, const void* sinS, const void* WqS,
    const void* WkS, const void* WvS, const void* WoS, const void* WqcS,
    const void* WkcS, const void* WvcS, const void* bqcS, const void* bkcS,
    const void* bvcS, const void* WdS, const void* bdS, const void* boS,
    const void* bqS, const void* bkS, const void* bvS,
    bf16* __restrict__ xb, bf16* __restrict__ WvB, bf16* __restrict__ WtQK,
    bf16* __restrict__ WtO, bf16* __restrict__ small, bf16* __restrict__ wctG,
    float* __restrict__ bo_part, int* __restrict__ flagW) {
  __shared__ __align__(16) char shm[16640];
  __shared__ int sflag;
  int blk = blockIdx.x;
  int t = threadIdx.x;

  // self-detect input dtype (wave 0 only; same 256-ushort probe as before)
  if (t < 64) {
    int bad = 0;
    for (int k = 0; k < 4; ++k) {
      ushort u = ((const ushort*)xS)[t * 4 + k];
      int ex = (u >> 7) & 0xFF;
      if (ex >= 0xC0) bad = 1;
    }
    unsigned long long bl = __ballot(bad);
    if (t == 0) sflag = (bl != 0ULL) ? 1 : 0;
  }
  __syncthreads();
  int f32 = sflag;
  if (blk == 0 && t == 0) *flagW = f32;

  if (blk < PB_T3) {
    // --- fold_bias partial: bo_part[kb][col] = sum_k bd[k&127]*Wo[k][col] ---
    float* red = (float*)shm;
    int nb = blk & 15, kb = blk >> 4;
    int col = nb * 128 + (t & 127);
    int half = t >> 7;
    float s = 0.f;
    int kbase = kb * 128 + half * 64;
    for (int i = 0; i < 64; ++i) {
      int k = kbase + i;
      s += cv1(bdS, k & 127, f32) * cv1(WoS, (size_t)k * 2048 + col, f32);
    }
    red[t] = s;
    __syncthreads();
    if (half == 0) bo_part[kb * 2048 + col] = red[t] + red[t + 128];
  } else if (blk < PB_WV) {
    // --- weight transpose (Wq, Wk, Wo) ---
    float (*tile)[65] = (float(*)[65])shm;
    int rem0 = blk - PB_T3;
    int z = rem0 >> 10, rem = rem0 & 1023;
    const void* W = (z == 0) ? WqS : (z == 1) ? WkS : WoS;
    bf16* Wt = (z == 2) ? WtO : (WtQK + (size_t)z * 2048 * 2048);
    int n0 = (rem & 31) * 64, k0 = (rem >> 5) * 64;
    int x = (t & 7) * 8, y = t >> 3;
    for (int p = 0; p < 2; ++p) {
      int r = y + p * 32;
      if (f32) {
        const float* src = (const float*)W + (size_t)(k0 + r) * 2048 + n0 + x;
        float4 a = *(const float4*)src;
        float4 b2 = *(const float4*)(src + 4);
        tile[r][x + 0] = a.x; tile[r][x + 1] = a.y; tile[r][x + 2] = a.z; tile[r][x + 3] = a.w;
        tile[r][x + 4] = b2.x; tile[r][x + 5] = b2.y; tile[r][x + 6] = b2.z; tile[r][x + 7] = b2.w;
      } else {
        const ushort* src = (const ushort*)W + (size_t)(k0 + r) * 2048 + n0 + x;
        uint4 u = *(const uint4*)src;
        bf16* e = (bf16*)&u;
        for (int jj = 0; jj < 8; ++jj) tile[r][x + jj] = __bfloat162float(e[jj]);
      }
    }
    __syncthreads();
    for (int p = 0; p < 2; ++p) {
      int n = y + p * 32;
      bf16 tmp[8] __attribute__((aligned(16)));
      for (int jj = 0; jj < 8; ++jj) tmp[jj] = __float2bfloat16(tile[x + jj][n]);
      *(uint4*)&Wt[(size_t)(n0 + n) * 2048 + k0 + x] = *(uint4*)tmp;
    }
  } else if (blk < PB_CX) {
    // --- Wv -> bf16 copy ---
    size_t e = ((size_t)(blk - PB_WV) * 256 + t) * 8;
    conv8(WvS, e, WvB, e, f32);
  } else if (blk < PB_SM) {
    // --- x -> bf16 copy ---
    size_t e = ((size_t)(blk - PB_CX) * 256 + t) * 8;
    conv8(xS, e, xb, e, f32);
  } else {
    // --- small-area + wctG prep ---
    int tid = (blk - PB_SM) * 256 + t;  // 0..40959
    if (tid < SM_TOT / 8) {
      size_t e = (size_t)tid * 8;
      const void* src;
      size_t so;
      if (e < SM_SIN) { src = cosS; so = e - SM_COS; }
      else if (e < SM_WC) { src = sinS; so = e - SM_SIN; }
      else if (e < SM_BC) { size_t r = e - SM_WC; src = (r < 4096) ? WqcS : (r < 8192) ? WkcS : WvcS; so = r & 4095; }
      else if (e < SM_WD) { size_t r = e - SM_BC; src = (r < 32) ? bqcS : (r < 64) ? bkcS : bvcS; so = r & 31; }
      else if (e < SM_BD) { src = WdS; so = e - SM_WD; }
      else if (e < SM_BO) { src = bdS; so = e - SM_BD; }
      else if (e < SM_BQKV) { src = boS; so = e - SM_BO; }
      else { size_t r = e - SM_BQKV; src = (r < 2048) ? bqS : (r < 4096) ? bkS : bvS; so = r & 2047; }
      conv8(src, so, small, e, f32);
    } else {
      int idx = tid - SM_TOT / 8;
      for (int i = idx; i < 12288; i += 40960 - SM_TOT / 8) {
        int reg = i >> 12, rem2 = i & 4095, n = rem2 >> 7, k = rem2 & 127;
        const void* src = (reg == 0) ? WqcS : (reg == 1) ? WkcS : WvcS;
        wctG[i] = __float2bfloat16(cv1(src, (size_t)k * 32 + n, f32));
      }
    }
  }
}

// ---------------- fold_all: fold_vw | fold_ow | fold_bias_final ----------------
__global__ __launch_bounds__(256) void fold_all(
    const bf16* __restrict__ WvB, const bf16* __restrict__ wctG,
    const bf16* __restrict__ WtO, const bf16* __restrict__ small,
    const void* boS, const float* __restrict__ bo_part, const void* bvS,
    const void* bvcS, const void* WvcS, bf16* __restrict__ Wvt,
    bf16* __restrict__ Wot, float* __restrict__ boF, float* __restrict__ bvF,
    const int* __restrict__ flagp) {
  int blk = blockIdx.x;
  int t = threadIdx.x, lane = t & 63, w = t >> 6;
  int qd = lane >> 4, ln = lane & 15;
  if (blk < 256) {
    // fold_vw: W~vt[(h*32+e)][d_in]
    int nb = blk & 15, h = blk >> 4;
    f32x4 acc[2][2] = {};
    for (int kt = 0; kt < 4; ++kt) {
      bf16x8 af[2], bfr[2];
      for (int i = 0; i < 2; ++i)
        af[i] = *(const bf16x8*)&wctG[8192 + (i * 16 + ln) * 128 + kt * 32 + qd * 8];
      for (int j = 0; j < 2; ++j)
        bfr[j] = *(const bf16x8*)&WvB[(size_t)(nb * 128 + w * 32 + j * 16 + ln) * 2048 +
                                      h * 128 + kt * 32 + qd * 8];
      for (int i = 0; i < 2; ++i)
        for (int j = 0; j < 2; ++j)
          acc[i][j] = __builtin_amdgcn_mfma_f32_16x16x32_bf16(af[i], bfr[j], acc[i][j], 0, 0, 0);
    }
    for (int i = 0; i < 2; ++i)
      for (int j = 0; j < 2; ++j)
        for (int r = 0; r < 4; ++r) {
          int e = i * 16 + qd * 4 + r;
          int col = nb * 128 + w * 32 + j * 16 + ln;
          Wvt[(size_t)(h * 32 + e) * 2048 + col] = __float2bfloat16(acc[i][j][r]);
        }
  } else if (blk < 512) {
    // fold_ow: W~ot[d_out][(h*32+e)]
    int rem = blk - 256;
    int mb = rem & 15, h = rem >> 4;
    f32x4 acc[2][2] = {};
    for (int kt = 0; kt < 4; ++kt) {
      bf16x8 af[2], bfr[2];
      for (int i = 0; i < 2; ++i)
        af[i] = *(const bf16x8*)&WtO[(size_t)(mb * 128 + w * 32 + i * 16 + ln) * 2048 +
                                     h * 128 + kt * 32 + qd * 8];
      for (int j = 0; j < 2; ++j)
        bfr[j] = *(const bf16x8*)&small[SM_WD + (j * 16 + ln) * 128 + kt * 32 + qd * 8];
      for (int i = 0; i < 2; ++i)
        for (int j = 0; j < 2; ++j)
          acc[i][j] = __builtin_amdgcn_mfma_f32_16x16x32_bf16(af[i], bfr[j], acc[i][j], 0, 0, 0);
    }
    for (int i = 0; i < 2; ++i)
      for (int j = 0; j < 2; ++j)
        for (int r = 0; r < 4; ++r) {
          int row = mb * 128 + w * 32 + i * 16 + qd * 4 + r;
          int col = h * 32 + j * 16 + ln;
          Wot[(size_t)row * 512 + col] = __float2bfloat16(acc[i][j][r]);
        }
  } else {
    // fold_bias_final
    int f32 = *flagp;
    int tid = (blk - 512) * 256 + t;  // 0..2559
    if (tid < 2048) {
      float s = cv1(boS, tid, f32);
      for (int kb = 0; kb < 16; ++kb) s += bo_part[kb * 2048 + tid];
      boF[tid] = s;
    } else if (tid < 2560) {
      int j = tid - 2048, h = j >> 5, e = j & 31;
      float s = cv1(bvcS, e, f32);
      for (int hd = 0; hd < 128; ++hd)
        s += cv1(bvS, h * 128 + hd, f32) * cv1(WvcS, (size_t)hd * 32 + e, f32);
      bvF[j] = s;
    }
  }
}

// ---------------- merged QKV: blocks 0..1023 = QK+RoPE+compress; 1024..1535 = V-fold ----------------
#define ESTR 136
__global__ __launch_bounds__(256) void gemm_qkv(
    const bf16* __restrict__ A, const bf16* __restrict__ Bt,
    const bf16* __restrict__ Wvt, const bf16* __restrict__ small,
    const bf16* __restrict__ wctG, const float* __restrict__ bvF,
    bf16* __restrict__ qc, bf16* __restrict__ kc, bf16* __restrict__ vcT) {
  __shared__ bf16 sh[128 * ESTR];  // 34816 B; first 16KB doubles as lA|lB
  const int K = 2048;
  int id = blockIdx.x;
  int t = threadIdx.x;
  int lane = t & 63, w = t >> 6;
  int qd = lane >> 4, ln = lane & 15;

  if (id < 1024) {
    // ---- QK path: bn fastest ----
    bf16* lA = sh;
    bf16* lB = sh + 4096;
    int bn = id & 31, bm = id >> 5;
    int reg = bn >> 4, h = bn & 15;
    int wm = (w >> 1) * 64, wn = (w & 1) * 64;

    f32x4 acc[4][4] = {};
    const bf16* Ab = A + (size_t)(bm * 128) * K;
    const bf16* Bb = Bt + (size_t)(bn * 128) * K;

    for (int kt = 0; kt < K; kt += 32) {
      for (int p = 0; p < 2; ++p) {
        int slot = t + p * 256;
        int r = slot >> 2, c = (slot & 3) * 8;
        GLDS16(&Ab[(size_t)r * K + kt + c], &lA[slot * 8]);
        GLDS16(&Bb[(size_t)r * K + kt + c], &lB[slot * 8]);
      }
      __syncthreads();
      bf16x8 af[4], bfr[4];
      for (int i = 0; i < 4; ++i) af[i] = *(bf16x8*)&lA[(wm + i * 16 + ln) * 32 + qd * 8];
      for (int j = 0; j < 4; ++j) bfr[j] = *(bf16x8*)&lB[(wn + j * 16 + ln) * 32 + qd * 8];
      for (int i = 0; i < 4; ++i)
        for (int j = 0; j < 4; ++j)
          acc[i][j] = __builtin_amdgcn_mfma_f32_16x16x32_bf16(af[i], bfr[j], acc[i][j], 0, 0, 0);
      __syncthreads();
    }

    // epilogue 1: acc + bias -> LDS tile
    for (int j = 0; j < 4; ++j) {
      int col = wn + j * 16 + ln;
      float bv = __bfloat162float(small[SM_BQKV + bn * 128 + col]);
      for (int i = 0; i < 4; ++i)
        for (int r = 0; r < 4; ++r)
          sh[(wm + i * 16 + qd * 4 + r) * ESTR + col] = __float2bfloat16(acc[i][j][r] + bv);
    }
    __syncthreads();

    // epilogue 2: RoPE + compress 32 l-rows per wave
    int r0 = w * 32;
    int b = bm >> 4;
    int bh = b * Hn + h;
    bf16x8 bfr2[2][4];
    for (int nt = 0; nt < 2; ++nt)
      for (int kt = 0; kt < 4; ++kt)
        bfr2[nt][kt] = *(const bf16x8*)&wctG[reg * 4096 + (nt * 16 + ln) * 128 + kt * 32 + qd * 8];
    float bc[2];
    bc[0] = __bfloat162float(small[SM_BC + reg * 32 + ln]);
    bc[1] = __bfloat162float(small[SM_BC + reg * 32 + 16 + ln]);

    for (int mt = 0; mt < 2; ++mt) {
      int lb = r0 + mt * 16 + ln;
      int lg2 = (bm & 15) * 128 + lb;
      f32x4 c2[2] = {};
      for (int kt = 0; kt < 4; ++kt) {
        uint4 u = *(uint4*)&sh[lb * ESTR + kt * 32 + qd * 8];
        bf16* e8 = (bf16*)&u;
        int pbase = kt * 16 + qd * 4;
        uint2 cu = *(const uint2*)&small[SM_COS + (size_t)lg2 * 64 + pbase];
        uint2 su = *(const uint2*)&small[SM_SIN + (size_t)lg2 * 64 + pbase];
        const bf16* cp = (const bf16*)&cu;
        const bf16* sp = (const bf16*)&su;
        for (int j = 0; j < 4; ++j) {
          float cvv = __bfloat162float(cp[j]);
          float svv = __bfloat162float(sp[j]);
          float ev = __bfloat162float(e8[2 * j]);
          float ov = __bfloat162float(e8[2 * j + 1]);
          e8[2 * j] = __float2bfloat16(ev * cvv - ov * svv);
          e8[2 * j + 1] = __float2bfloat16(ev * svv + ov * cvv);
        }
        bf16x8 a = *(bf16x8*)&u;
        c2[0] = __builtin_amdgcn_mfma_f32_16x16x32_bf16(a, bfr2[0][kt], c2[0], 0, 0, 0);
        c2[1] = __builtin_amdgcn_mfma_f32_16x16x32_bf16(a, bfr2[1][kt], c2[1], 0, 0, 0);
      }
      int lgbase = (bm & 15) * 128 + r0 + mt * 16 + qd * 4;
      bf16* dst = (reg == 0) ? qc : kc;
      for (int nt = 0; nt < 2; ++nt)
        for (int r = 0; r < 4; ++r)
          dst[((size_t)bh * Lseq + lgbase + r) * 32 + nt * 16 + ln] =
              __float2bfloat16(c2[nt][r] + bc[nt]);
    }
  } else {
    // ---- V-fold path: vcT[(b*512+n)][l] = x @ W~vt^T + bvF ----
    bf16* lA = sh;
    bf16* lB = sh + 2048;  // 64*32 elements each
    int rem = id - 1024;
    int nb = rem & 7, bm = rem >> 3;
    int wm = (w >> 1) * 32, wn = (w & 1) * 32;

    f32x4 acc[2][2] = {};
    const bf16* Ab = A + (size_t)(bm * 64) * K;
    const bf16* Bb = Wvt + (size_t)(nb * 64) * K;

    int r = t >> 2, c = (t & 3) * 8;
    for (int kt = 0; kt < K; kt += 32) {
      GLDS16(&Ab[(size_t)r * K + kt + c], &lA[t * 8]);
      GLDS16(&Bb[(size_t)r * K + kt + c], &lB[t * 8]);
      __syncthreads();
      bf16x8 af[2], bfr[2];
      for (int i = 0; i < 2; ++i) af[i] = *(bf16x8*)&lA[(wm + i * 16 + ln) * 32 + qd * 8];
      for (int j = 0; j < 2; ++j) bfr[j] = *(bf16x8*)&lB[(wn + j * 16 + ln) * 32 + qd * 8];
      for (int i = 0; i < 2; ++i)
        for (int j = 0; j < 2; ++j)
          acc[i][j] = __builtin_amdgcn_mfma_f32_16x16x32_bf16(af[i], bfr[j], acc[i][j], 0, 0, 0);
      __syncthreads();
    }

    int b = bm >> 5;
    for (int j = 0; j < 2; ++j) {
      int n = nb * 64 + wn + j * 16 + ln;
      float bb = bvF[n];
      for (int i = 0; i < 2; ++i) {
        int lloc = (bm & 31) * 64 + wm + i * 16 + qd * 4;
        bf16 p4[4] __attribute__((aligned(8)));
        for (int rr = 0; rr < 4; ++rr) p4[rr] = __float2bfloat16(acc[i][j][rr] + bb);
        *(uint2*)&vcT[((size_t)(b * 512 + n)) * 2048 + lloc] = *(uint2*)p4;
      }
    }
  }
}

// ---------------- output GEMM: d_out = attn @ Wot^T + boF (fp32 bias), K=512 ----------------
__global__ __launch_bounds__(256) void gemm_bias_out(const bf16* __restrict__ A,
                                                     const bf16* __restrict__ Bt,
                                                     const float* __restrict__ bias,
                                                     void* __restrict__ C,
                                                     int M, int N, int K,
                                                     const int* __restrict__ flagp) {
  __shared__ bf16 lA[128 * 32];
  __shared__ bf16 lB[128 * 32];
  int f32out = *flagp;
  int bm = blockIdx.y, bn = blockIdx.x;
  int t = threadIdx.x;
  int lane = t & 63, w = t >> 6;
  int wm = (w >> 1) * 64, wn = (w & 1) * 64;
  int qd = lane >> 4, ln = lane & 15;

  f32x4 acc[4][4] = {};
  const bf16* Ab = A + (size_t)(bm * 128) * K;
  const bf16* Bb = Bt + (size_t)(bn * 128) * K;

  for (int kt = 0; kt < K; kt += 32) {
    for (int p = 0; p < 2; ++p) {
      int slot = t + p * 256;
      int r = slot >> 2, c = (slot & 3) * 8;
      GLDS16(&Ab[(size_t)r * K + kt + c], &lA[slot * 8]);
      GLDS16(&Bb[(size_t)r * K + kt + c], &lB[slot * 8]);
    }
    __syncthreads();
    bf16x8 af[4], bfr[4];
    for (int i = 0; i < 4; ++i) af[i] = *(bf16x8*)&lA[(wm + i * 16 + ln) * 32 + qd * 8];
    for (int j = 0; j < 4; ++j) bfr[j] = *(bf16x8*)&lB[(wn + j * 16 + ln) * 32 + qd * 8];
    for (int i = 0; i < 4; ++i)
      for (int j = 0; j < 4; ++j)
        acc[i][j] = __builtin_amdgcn_mfma_f32_16x16x32_bf16(af[i], bfr[j], acc[i][j], 0, 0, 0);
    __syncthreads();
  }
  for (int i = 0; i < 4; ++i)
    for (int j = 0; j < 4; ++j) {
      int col = bn * 128 + wn + j * 16 + ln;
      float bv = bias[col];
      for (int r = 0; r < 4; ++r) {
        int row = bm * 128 + wm + i * 16 + qd * 4 + r;
        float v = acc[i][j][r] + bv;
        if (f32out) ((float*)C)[(size_t)row * N + col] = v;
        else ((bf16*)C)[(size_t)row * N + col] = __float2bfloat16(v);
      }
    }
}

// ---------------- flash attention: 64-key chunks, prefetch, exp2, T13 defer-max ----------------
__global__ __launch_bounds__(256) void flash32(const bf16* __restrict__ qc,
                                               const bf16* __restrict__ kc,
                                               const bf16* __restrict__ vcT,
                                               bf16* __restrict__ attn) {
  __shared__ bf16 pbuf[4][16 * 72];     // 9216 B
  __shared__ float oL[4][16][33];       // 8448 B
  __shared__ float mL[4][16];
  __shared__ float lsL[4][16];
  int t = threadIdx.x;
  int lane = t & 63, w = t >> 6;
  int qd = lane >> 4, ln = lane & 15;
  int blk = blockIdx.x;                 // grid 4096 = 32 bh x 128 q-tiles
  int j = blk & 127;
  int bh = blk >> 7, h = bh & 15, b = bh >> 4;
  int q0 = j * 16;

  bf16x8 qf = *(const bf16x8*)&qc[((size_t)bh * Lseq + q0 + ln) * 32 + qd * 8];

  f32x4 o0 = {}, o1 = {};
  float m[4], ls[4];
  for (int r = 0; r < 4; ++r) { m[r] = -1e30f; ls[r] = 0.f; }
  const float scale2 = 0.17677669529663687f * 1.4426950408889634f;

  int n64 = (q0 + 16 + 63) >> 6;        // causal KV chunks of 64
  int nw = (n64 + 3) >> 2;
  int c0 = w * nw;
  int c1 = min(c0 + nw, n64);

  bf16* pb = pbuf[w];
  bf16x8 kf[4];
  if (c0 < c1) {
    int k0 = c0 * 64;
    for (int c = 0; c < 4; ++c)
      kf[c] = *(const bf16x8*)&kc[((size_t)bh * Lseq + k0 + c * 16 + ln) * 32 + qd * 8];
  }
  for (int ci = c0; ci < c1; ++ci) {
    int k0 = ci * 64;
    f32x4 s[4];
    for (int c = 0; c < 4; ++c) {
      f32x4 z = {};
      s[c] = __builtin_amdgcn_mfma_f32_16x16x32_bf16(qf, kf[c], z, 0, 0, 0);
    }
    // issue V(this chunk) + K(next chunk) loads BEFORE the softmax chain
    size_t vbase = ((size_t)bh * 32 + ln) * Lseq + k0 + qd * 8;
    bf16x8 vf00 = *(const bf16x8*)&vcT[vbase];
    bf16x8 vf01 = *(const bf16x8*)&vcT[vbase + 32];
    bf16x8 vf10 = *(const bf16x8*)&vcT[vbase + (size_t)16 * Lseq];
    bf16x8 vf11 = *(const bf16x8*)&vcT[vbase + (size_t)16 * Lseq + 32];
    if (ci + 1 < c1) {
      int k0n = k0 + 64;
      for (int c = 0; c < 4; ++c)
        kf[c] = *(const bf16x8*)&kc[((size_t)bh * Lseq + k0n + c * 16 + ln) * 32 + qd * 8];
    }
    float sv[4][4];
    for (int r = 0; r < 4; ++r) {
      int qrow = q0 + qd * 4 + r;
      for (int c = 0; c < 4; ++c)
        sv[c][r] = (k0 + c * 16 + ln <= qrow) ? s[c][r] * scale2 : -1e30f;
    }
    for (int r = 0; r < 4; ++r) {
      float mx = fmaxf(fmaxf(sv[0][r], sv[1][r]), fmaxf(sv[2][r], sv[3][r]));
      for (int off = 1; off < 16; off <<= 1) mx = fmaxf(mx, __shfl_xor(mx, off, 64));
      // T13 defer-max: skip rescale when chunk max within 8 of running max
      // (exp2-domain: P values then bounded by 2^8; exact online-softmax algebra)
      if (!__all(mx <= m[r] + 8.f)) {
        float mn = fmaxf(m[r], mx);
        float alpha = exp2f(m[r] - mn);
        m[r] = mn;
        ls[r] *= alpha;
        o0[r] *= alpha;
        o1[r] *= alpha;
      }
      float rs = 0.f;
      for (int c = 0; c < 4; ++c) { sv[c][r] = exp2f(sv[c][r] - m[r]); rs += sv[c][r]; }
      ls[r] += rs;
    }
    for (int r = 0; r < 4; ++r)
      for (int c = 0; c < 4; ++c)
        pb[(qd * 4 + r) * 72 + c * 16 + ln] = __float2bfloat16(sv[c][r]);
    asm volatile("s_waitcnt lgkmcnt(0)" ::: "memory");
    bf16x8 pf0 = *(bf16x8*)&pb[ln * 72 + qd * 8];
    bf16x8 pf1 = *(bf16x8*)&pb[ln * 72 + 32 + qd * 8];
    o0 = __builtin_amdgcn_mfma_f32_16x16x32_bf16(pf0, vf00, o0, 0, 0, 0);
    o0 = __builtin_amdgcn_mfma_f32_16x16x32_bf16(pf1, vf01, o0, 0, 0, 0);
    o1 = __builtin_amdgcn_mfma_f32_16x16x32_bf16(pf0, vf10, o1, 0, 0, 0);
    o1 = __builtin_amdgcn_mfma_f32_16x16x32_bf16(pf1, vf11, o1, 0, 0, 0);
  }

  for (int r = 0; r < 4; ++r)
    for (int off = 1; off < 16; off <<= 1) ls[r] += __shfl_xor(ls[r], off, 64);

  for (int r = 0; r < 4; ++r) {
    int row = qd * 4 + r;
    oL[w][row][ln] = o0[r];
    oL[w][row][16 + ln] = o1[r];
    if (ln == 0) { mL[w][row] = m[r]; lsL[w][row] = ls[r]; }
  }
  __syncthreads();

  for (int idx = t; idx < 512; idx += 256) {
    int row = idx >> 5, col = idx & 31;
    float m0 = mL[0][row], m1 = mL[1][row], m2 = mL[2][row], m3 = mL[3][row];
    float ms = fmaxf(fmaxf(m0, m1), fmaxf(m2, m3));
    float e0 = exp2f(m0 - ms), e1 = exp2f(m1 - ms);
    float e2 = exp2f(m2 - ms), e3 = exp2f(m3 - ms);
    float lsum = lsL[0][row] * e0 + lsL[1][row] * e1 + lsL[2][row] * e2 + lsL[3][row] * e3;
    float val = oL[0][row][col] * e0 + oL[1][row][col] * e1 +
                oL[2][row][col] * e2 + oL[3][row][col] * e3;
    int l = q0 + row;
    attn[((size_t)(b * Lseq + l)) * 512 + h * 32 + col] = __float2bfloat16(val / lsum);
  }
}

extern "C" void kernel_launch(void* const* d_in, const int* in_sizes, int n_in,
                              void* d_out, int out_size, void* d_ws, size_t ws_size,
                              hipStream_t stream) {
  const void* x = d_in[0];
  const void* cosS = d_in[1];
  const void* sinS = d_in[2];
  const void* Wq = d_in[3];
  const void* bq = d_in[4];
  const void* Wk = d_in[5];
  const void* bk = d_in[6];
  const void* Wv = d_in[7];
  const void* bv = d_in[8];
  const void* Wqc = d_in[9];
  const void* bqc = d_in[10];
  const void* Wkc = d_in[11];
  const void* bkc = d_in[12];
  const void* Wvc = d_in[13];
  const void* bvc = d_in[14];
  const void* Wd = d_in[15];
  const void* bd = d_in[16];
  const void* Wo = d_in[17];
  const void* bo = d_in[18];

  char* ws = (char*)d_ws;
  size_t off = 0;
  auto alloc = [&](size_t bytes) {
    char* p = ws + off;
    off += (bytes + 255) & ~(size_t)255;
    return p;
  };
  int* flag = (int*)alloc(256);
  bf16* small = (bf16*)alloc((size_t)SM_TOT * 2);
  bf16* wctG = (bf16*)alloc((size_t)12288 * 2);
  bf16* xb = (bf16*)alloc((size_t)4096 * 2048 * 2);
  bf16* WvB = (bf16*)alloc((size_t)2048 * 2048 * 2);
  bf16* WtQK = (bf16*)alloc((size_t)4096 * 2048 * 2);
  bf16* WtO = (bf16*)alloc((size_t)2048 * 2048 * 2);
  bf16* Wvt = (bf16*)alloc((size_t)512 * 2048 * 2);
  bf16* Wot = (bf16*)alloc((size_t)2048 * 512 * 2);
  float* bo_part = (float*)alloc((size_t)16 * 2048 * 4);
  float* boF = (float*)alloc((size_t)2048 * 4);
  float* bvF = (float*)alloc((size_t)512 * 4);
  bf16* qcW = (bf16*)alloc((size_t)65536 * 32 * 2);
  bf16* kcW = (bf16*)alloc((size_t)65536 * 32 * 2);
  bf16* vcTW = (bf16*)alloc((size_t)65536 * 32 * 2);
  bf16* attnW = (bf16*)alloc((size_t)4096 * 512 * 2);

  dim3 tb(256);
  prep_all<<<NB_PREP_ALL, tb, 0, stream>>>(
      x, cosS, sinS, Wq, Wk, Wv, Wo, Wqc, Wkc, Wvc, bqc, bkc, bvc, Wd, bd, bo,
      bq, bk, bv, xb, WvB, WtQK, WtO, small, wctG, bo_part, flag);
  fold_all<<<522, tb, 0, stream>>>(WvB, wctG, WtO, small, bo, bo_part, bv, bvc,
                                   Wvc, Wvt, Wot, boF, bvF, flag);
  gemm_qkv<<<1536, tb, 0, stream>>>(xb, WtQK, Wvt, small, wctG, bvF, qcW, kcW, vcTW);
  flash32<<<4096, tb, 0, stream>>>(qcW, kcW, vcTW, attnW);
  gemm_bias_out<<<dim3(16, 32), tb, 0, stream>>>(attnW, Wot, boF, d_out, 4096, 2048,
                                                 512, flag);
}